// Round 5
// baseline (731.260 us; speedup 1.0000x reference)
//
#include <hip/hip_runtime.h>
#include <hip/hip_bf16.h>
#include <stdint.h>

typedef __attribute__((ext_vector_type(8))) short bf16x8;
typedef __attribute__((ext_vector_type(4))) float f32x4;

typedef const __attribute__((address_space(1))) void* gas_ptr;
typedef __attribute__((address_space(3))) void* lds_ptr_t;

__device__ __forceinline__ unsigned short f32_to_bf16_rtn(float x) {
    unsigned u = __float_as_uint(x);
    u += 0x7FFFu + ((u >> 16) & 1u);
    return (unsigned short)(u >> 16);
}
__device__ __forceinline__ float bf16_bits_to_f32(unsigned short h) {
    return __uint_as_float(((unsigned)h) << 16);
}

// ---------------------------------------------------------------------------
// Kernel 1: split fp32 inputs into hi/lo bf16 pairs (a = hi + lo, err ~2^-17)
// ---------------------------------------------------------------------------
__global__ __launch_bounds__(256) void split_hi_lo(
    const float* __restrict__ A, const float* __restrict__ B,
    unsigned short* __restrict__ Ahi, unsigned short* __restrict__ Alo,
    unsigned short* __restrict__ Bhi, unsigned short* __restrict__ Blo, int n4)
{
    int i = blockIdx.x * 256 + threadIdx.x;
    if (i >= n4) return;
    float4 a = ((const float4*)A)[i];
    float4 b = ((const float4*)B)[i];
    ushort4 h, l;

    h.x = f32_to_bf16_rtn(a.x); l.x = f32_to_bf16_rtn(a.x - bf16_bits_to_f32(h.x));
    h.y = f32_to_bf16_rtn(a.y); l.y = f32_to_bf16_rtn(a.y - bf16_bits_to_f32(h.y));
    h.z = f32_to_bf16_rtn(a.z); l.z = f32_to_bf16_rtn(a.z - bf16_bits_to_f32(h.z));
    h.w = f32_to_bf16_rtn(a.w); l.w = f32_to_bf16_rtn(a.w - bf16_bits_to_f32(h.w));
    ((ushort4*)Ahi)[i] = h; ((ushort4*)Alo)[i] = l;

    h.x = f32_to_bf16_rtn(b.x); l.x = f32_to_bf16_rtn(b.x - bf16_bits_to_f32(h.x));
    h.y = f32_to_bf16_rtn(b.y); l.y = f32_to_bf16_rtn(b.y - bf16_bits_to_f32(h.y));
    h.z = f32_to_bf16_rtn(b.z); l.z = f32_to_bf16_rtn(b.z - bf16_bits_to_f32(h.z));
    h.w = f32_to_bf16_rtn(b.w); l.w = f32_to_bf16_rtn(b.w - bf16_bits_to_f32(h.w));
    ((ushort4*)Bhi)[i] = h; ((ushort4*)Blo)[i] = l;
}

// ---------------------------------------------------------------------------
// Kernel 2 (presplit, hot path): energies = A @ B^T, split-bf16 3-product GEMM.
// 16x16x32 mfma, 4x4 tiles/wave, 128x128 block, BK=32.
// XOR swizzle on 16B chunks: SQ_LDS_BANK_CONFLICT == 0 measured.
// NO min-waves launch bound (forced 128-reg budget -> spills).
// NO XCD blockIdx swizzle: r1 measured FETCH 323 MB -> 1.4 GB, MfmaUtil 52->37.
// r4: constexpr dims + unroll x4 -> VALUBusy 43->23.6 (confirmed), but
// MfmaUtil only 52->53: not issue-bound. Residual ~23% idle = memory-latency
// waits at the per-K-step vmcnt(0) drains.
// r5 THEORY: FETCH 476 MB vs 64 MB unique input = 7.4x refetch. The 262 MB
// C-store stream cycles the entire 256 MB L3 every dispatch, evicting the
// B panels -> staged loads pay HBM latency (~900cy) inside every barrier
// drain. FIX: nontemporal C stores (no-allocate) -> L3 keeps A/B resident.
// Predict FETCH -> ~80-150 MB, MfmaUtil 53 -> ~60, dur 370 -> ~310.
// ---------------------------------------------------------------------------
template<int KC, int NC>
__global__ __launch_bounds__(256) void gemm_presplit(
    const __hip_bfloat16* __restrict__ Ahi, const __hip_bfloat16* __restrict__ Alo,
    const __hip_bfloat16* __restrict__ Bhi, const __hip_bfloat16* __restrict__ Blo,
    float* __restrict__ out, int M, int N, int K)
{
    const int Kd = (KC > 0) ? KC : K;   // compile-time when KC>0
    const int Nd = (NC > 0) ? NC : N;

    __shared__ char sm[32768];   // [0,8K)=Ahi [8K,16K)=Alo [16K,24K)=Bhi [24K,32K)=Blo
    const int tid  = threadIdx.x;
    const int lane = tid & 63;
    const int w    = tid >> 6;
    const int bm = blockIdx.y, bn = blockIdx.x;
    const int wm = (w >> 1) * 64;
    const int wn = (w & 1) * 64;

    f32x4 acc[4][4] = {};

    // staging: thread owns LDS chunk (row=(c&1)*64 + tid>>2, pos=tid&3);
    // fetches source chunk (tid&3) ^ ((row>>1)&3) = (tid&3) ^ ((tid>>3)&3)
    const int sfetch = (tid & 3) ^ ((tid >> 3) & 3);
    const size_t offA = (size_t)(bm * 128 + (tid >> 2)) * Kd + sfetch * 8;
    const size_t offB = (size_t)(bn * 128 + (tid >> 2)) * Kd + sfetch * 8;
    const __hip_bfloat16* pAh = Ahi + offA;
    const __hip_bfloat16* pAl = Alo + offA;
    const __hip_bfloat16* pBh = Bhi + offB;
    const __hip_bfloat16* pBl = Blo + offB;
    const size_t half = (size_t)64 * Kd;   // +64 rows
    char* dst0 = sm + tid * 16;

    // read side: fragment chunk = lane>>4, swizzled: ^ ((lane>>1)&3)
    const int rA = lane & 15;
    const int ca = (lane >> 4) ^ ((lane >> 1) & 3);
    const char* aP = sm +         (wm + rA) * 64 + ca * 16;   // A-hi base
    const char* bP = sm + 16384 + (wn + rA) * 64 + ca * 16;   // B-hi base

#pragma unroll 4
    for (int k0 = 0; k0 < Kd; k0 += 32) {
        __syncthreads();
        __builtin_amdgcn_global_load_lds((gas_ptr)(pAh + k0),        (lds_ptr_t)(dst0),         16, 0, 0);
        __builtin_amdgcn_global_load_lds((gas_ptr)(pAh + half + k0), (lds_ptr_t)(dst0 + 4096),  16, 0, 0);
        __builtin_amdgcn_global_load_lds((gas_ptr)(pAl + k0),        (lds_ptr_t)(dst0 + 8192),  16, 0, 0);
        __builtin_amdgcn_global_load_lds((gas_ptr)(pAl + half + k0), (lds_ptr_t)(dst0 + 12288), 16, 0, 0);
        __builtin_amdgcn_global_load_lds((gas_ptr)(pBh + k0),        (lds_ptr_t)(dst0 + 16384), 16, 0, 0);
        __builtin_amdgcn_global_load_lds((gas_ptr)(pBh + half + k0), (lds_ptr_t)(dst0 + 20480), 16, 0, 0);
        __builtin_amdgcn_global_load_lds((gas_ptr)(pBl + k0),        (lds_ptr_t)(dst0 + 24576), 16, 0, 0);
        __builtin_amdgcn_global_load_lds((gas_ptr)(pBl + half + k0), (lds_ptr_t)(dst0 + 28672), 16, 0, 0);
        __syncthreads();

        bf16x8 bh[4], bl[4];
#pragma unroll
        for (int j = 0; j < 4; ++j) {
            bh[j] = *(const bf16x8*)(bP + j * 1024);
            bl[j] = *(const bf16x8*)(bP + j * 1024 + 8192);
        }
#pragma unroll
        for (int i = 0; i < 4; ++i) {
            bf16x8 ah = *(const bf16x8*)(aP + i * 1024);
            bf16x8 al = *(const bf16x8*)(aP + i * 1024 + 8192);
#pragma unroll
            for (int j = 0; j < 4; ++j) {
                acc[i][j] = __builtin_amdgcn_mfma_f32_16x16x32_bf16(ah, bh[j], acc[i][j], 0, 0, 0);
                acc[i][j] = __builtin_amdgcn_mfma_f32_16x16x32_bf16(al, bh[j], acc[i][j], 0, 0, 0);
                acc[i][j] = __builtin_amdgcn_mfma_f32_16x16x32_bf16(ah, bl[j], acc[i][j], 0, 0, 0);
            }
        }
    }

    // Epilogue: 16x16 C/D layout col=lane&15, row=(lane>>4)*4+reg (m89/m91).
    // r5: NONTEMPORAL stores — C is 256 MB (> L3), zero reuse before the
    // softmax streams it; caching it evicts the B panels the K-loop needs.
    const int r0 = bm * 128 + wm + ((lane >> 4) << 2);
    const int c0 = bn * 128 + wn + rA;
#pragma unroll
    for (int i = 0; i < 4; ++i)
#pragma unroll
        for (int j = 0; j < 4; ++j)
#pragma unroll
            for (int r = 0; r < 4; ++r)
                __builtin_nontemporal_store(
                    acc[i][j][r],
                    &out[(size_t)(r0 + i * 16 + r) * Nd + (c0 + j * 16)]);
}

// ---------------------------------------------------------------------------
// Kernel 2b (fallback, ws too small — not expected to run): inline split.
// ---------------------------------------------------------------------------
__global__ __launch_bounds__(256) void gemm_fallback(
    const float* __restrict__ Af, const float* __restrict__ Bf,
    float* __restrict__ out, int M, int N, int K)
{
    __shared__ char sm[32768];
    const int tid  = threadIdx.x;
    const int lane = tid & 63;
    const int w    = tid >> 6;
    const int bm = blockIdx.y, bn = blockIdx.x;
    const int wm = (w >> 1) * 64;
    const int wn = (w & 1) * 64;

    f32x4 acc[4][4] = {};
    const int sfetch = (tid & 3) ^ ((tid >> 3) & 3);
    const int rA = lane & 15;
    const int ca = (lane >> 4) ^ ((lane >> 1) & 3);
    const char* aP = sm +         (wm + rA) * 64 + ca * 16;
    const char* bP = sm + 16384 + (wn + rA) * 64 + ca * 16;

    for (int k0 = 0; k0 < K; k0 += 32) {
        __syncthreads();
#pragma unroll
        for (int c = 0; c < 4; ++c) {
            const bool isA = (c < 2);
            const int row = ((c & 1) << 6) + (tid >> 2);
            const float* src = (isA ? Af + (size_t)(bm * 128 + row) * K
                                    : Bf + (size_t)(bn * 128 + row) * K)
                               + k0 + ((tid & 3) << 3);
            f32x4 v0 = *(const f32x4*)src;
            f32x4 v1 = *(const f32x4*)(src + 4);
            float vv[8] = {v0.x, v0.y, v0.z, v0.w, v1.x, v1.y, v1.z, v1.w};
            bf16x8 h, l;
#pragma unroll
            for (int j = 0; j < 8; ++j) {
                unsigned short hb = f32_to_bf16_rtn(vv[j]);
                unsigned short lb = f32_to_bf16_rtn(vv[j] - bf16_bits_to_f32(hb));
                h[j] = (short)hb; l[j] = (short)lb;
            }
            const int g = row * 64 + sfetch * 16;
            *(bf16x8*)(sm + (isA ? 0 : 16384) + g) = h;
            *(bf16x8*)(sm + (isA ? 8192 : 24576) + g) = l;
        }
        __syncthreads();

        bf16x8 bh[4], bl[4];
#pragma unroll
        for (int j = 0; j < 4; ++j) {
            bh[j] = *(const bf16x8*)(bP + j * 1024);
            bl[j] = *(const bf16x8*)(bP + j * 1024 + 8192);
        }
#pragma unroll
        for (int i = 0; i < 4; ++i) {
            bf16x8 ah = *(const bf16x8*)(aP + i * 1024);
            bf16x8 al = *(const bf16x8*)(aP + i * 1024 + 8192);
#pragma unroll
            for (int j = 0; j < 4; ++j) {
                acc[i][j] = __builtin_amdgcn_mfma_f32_16x16x32_bf16(ah, bh[j], acc[i][j], 0, 0, 0);
                acc[i][j] = __builtin_amdgcn_mfma_f32_16x16x32_bf16(al, bh[j], acc[i][j], 0, 0, 0);
                acc[i][j] = __builtin_amdgcn_mfma_f32_16x16x32_bf16(ah, bl[j], acc[i][j], 0, 0, 0);
            }
        }
    }

    const int r0 = bm * 128 + wm + ((lane >> 4) << 2);
    const int c0 = bn * 128 + wn + rA;
#pragma unroll
    for (int i = 0; i < 4; ++i)
#pragma unroll
        for (int j = 0; j < 4; ++j)
#pragma unroll
            for (int r = 0; r < 4; ++r)
                __builtin_nontemporal_store(
                    acc[i][j][r],
                    &out[(size_t)(r0 + i * 16 + r) * N + (c0 + j * 16)]);
}

// ---------------------------------------------------------------------------
// Kernel 3: in-place row softmax. r0 (3-barrier), r1 (pipeline+syncthreads),
// r3 (pipeline+lgkm-only barriers) all measured the SAME non-gemm remainder
// (~320-350 us) -> softmax-structure theories refuted; remainder is likely
// dominated by harness reset/launch overhead. Keeping the r3 version
// (passed, equal perf). Do not touch further.
// ---------------------------------------------------------------------------
__device__ __forceinline__ void lgkm_barrier()
{
    asm volatile("s_waitcnt lgkmcnt(0)" ::: "memory");
    __builtin_amdgcn_s_barrier();
    asm volatile("" ::: "memory");
}

__device__ __forceinline__ void softmax_row(
    f32x4 (&v)[8], f32x4 (&vn)[8], const f32x4* __restrict__ pn, bool pref,
    f32x4* __restrict__ pout, int tid, int slot,
    float (*smax)[4], float (*ssum)[4])
{
    if (pref) {
#pragma unroll
        for (int i = 0; i < 8; ++i) vn[i] = pn[tid + (i << 8)];
    }
    float m = -3.402823466e+38f;
#pragma unroll
    for (int i = 0; i < 8; ++i)
        m = fmaxf(m, fmaxf(fmaxf(v[i].x, v[i].y), fmaxf(v[i].z, v[i].w)));
#pragma unroll
    for (int o = 32; o >= 1; o >>= 1) m = fmaxf(m, __shfl_xor(m, o));
    if ((tid & 63) == 0) smax[slot][tid >> 6] = m;
    lgkm_barrier();
    m = fmaxf(fmaxf(smax[slot][0], smax[slot][1]), fmaxf(smax[slot][2], smax[slot][3]));

    float s = 0.f;
#pragma unroll
    for (int i = 0; i < 8; ++i) {
        v[i].x = __expf(v[i].x - m);
        v[i].y = __expf(v[i].y - m);
        v[i].z = __expf(v[i].z - m);
        v[i].w = __expf(v[i].w - m);
        s += (v[i].x + v[i].y) + (v[i].z + v[i].w);
    }
#pragma unroll
    for (int o = 32; o >= 1; o >>= 1) s += __shfl_xor(s, o);
    if ((tid & 63) == 0) ssum[slot][tid >> 6] = s;
    lgkm_barrier();
    s = (ssum[slot][0] + ssum[slot][1]) + (ssum[slot][2] + ssum[slot][3]);
    const float r = 1.0f / s;
#pragma unroll
    for (int i = 0; i < 8; ++i) {
        v[i] *= r;
        __builtin_nontemporal_store(v[i], &pout[tid + (i << 8)]);
    }
}

__global__ __launch_bounds__(256) void softmax_rows_8192(float* __restrict__ d)
{
    const int tid = threadIdx.x;
    __shared__ float smax[2][4], ssum[2][4];

    f32x4* p0 = (f32x4*)(d + (size_t)blockIdx.x * 4 * 8192);
    f32x4 va[8], vb[8];
#pragma unroll
    for (int i = 0; i < 8; ++i) va[i] = p0[tid + (i << 8)];

    softmax_row(va, vb, p0 + 2048, true,  p0,        tid, 0, smax, ssum);
    softmax_row(vb, va, p0 + 4096, true,  p0 + 2048, tid, 1, smax, ssum);
    softmax_row(va, vb, p0 + 6144, true,  p0 + 4096, tid, 0, smax, ssum);
    softmax_row(vb, va, p0,        false, p0 + 6144, tid, 1, smax, ssum);
}

// ---------------------------------------------------------------------------
extern "C" void kernel_launch(void* const* d_in, const int* in_sizes, int n_in,
                              void* d_out, int out_size, void* d_ws, size_t ws_size,
                              hipStream_t stream)
{
    const float* A = (const float*)d_in[0];   // user_emb [M, K] fp32
    const float* B = (const float*)d_in[1];   // id_emb   [N, K] fp32
    float* out = (float*)d_out;               // [M, N] fp32
    const int K = 1024;
    const int M = in_sizes[0] / K;
    const int N = in_sizes[1] / K;
    const size_t elemsA = (size_t)M * K;
    const size_t elemsB = (size_t)N * K;
    const size_t need = 2 * (elemsA + elemsB) * sizeof(unsigned short);

    dim3 grid(N / 128, M / 128);
    const bool presplit = (ws_size >= need) && (M == N);

    if (presplit) {
        unsigned short* Ahi = (unsigned short*)d_ws;
        unsigned short* Alo = Ahi + elemsA;
        unsigned short* Bhi = Alo + elemsA;
        unsigned short* Blo = Bhi + elemsB;
        const int n4 = (int)(elemsA / 4);
        split_hi_lo<<<(n4 + 255) / 256, 256, 0, stream>>>(A, B, Ahi, Alo, Bhi, Blo, n4);
        if (K == 1024 && N == 8192) {
            gemm_presplit<1024, 8192><<<grid, 256, 0, stream>>>(
                (const __hip_bfloat16*)Ahi, (const __hip_bfloat16*)Alo,
                (const __hip_bfloat16*)Bhi, (const __hip_bfloat16*)Blo,
                out, M, N, K);
        } else {
            gemm_presplit<0, 0><<<grid, 256, 0, stream>>>(
                (const __hip_bfloat16*)Ahi, (const __hip_bfloat16*)Alo,
                (const __hip_bfloat16*)Bhi, (const __hip_bfloat16*)Blo,
                out, M, N, K);
        }
    } else {
        gemm_fallback<<<grid, 256, 0, stream>>>(A, B, out, M, N, K);
    }
    softmax_rows_8192<<<M / 4, 256, 0, stream>>>(out);
}

// Round 6
// 722.975 us; speedup vs baseline: 1.0115x; 1.0115x over previous
//
#include <hip/hip_runtime.h>
#include <hip/hip_bf16.h>
#include <stdint.h>

typedef __attribute__((ext_vector_type(8))) short bf16x8;
typedef __attribute__((ext_vector_type(4))) float f32x4;

typedef const __attribute__((address_space(1))) void* gas_ptr;
typedef __attribute__((address_space(3))) void* lds_ptr_t;

__device__ __forceinline__ unsigned short f32_to_bf16_rtn(float x) {
    unsigned u = __float_as_uint(x);
    u += 0x7FFFu + ((u >> 16) & 1u);
    return (unsigned short)(u >> 16);
}
__device__ __forceinline__ float bf16_bits_to_f32(unsigned short h) {
    return __uint_as_float(((unsigned)h) << 16);
}

// ---------------------------------------------------------------------------
// Kernel 1: split fp32 inputs into hi/lo bf16 pairs (a = hi + lo, err ~2^-17)
// ---------------------------------------------------------------------------
__global__ __launch_bounds__(256) void split_hi_lo(
    const float* __restrict__ A, const float* __restrict__ B,
    unsigned short* __restrict__ Ahi, unsigned short* __restrict__ Alo,
    unsigned short* __restrict__ Bhi, unsigned short* __restrict__ Blo, int n4)
{
    int i = blockIdx.x * 256 + threadIdx.x;
    if (i >= n4) return;
    float4 a = ((const float4*)A)[i];
    float4 b = ((const float4*)B)[i];
    ushort4 h, l;

    h.x = f32_to_bf16_rtn(a.x); l.x = f32_to_bf16_rtn(a.x - bf16_bits_to_f32(h.x));
    h.y = f32_to_bf16_rtn(a.y); l.y = f32_to_bf16_rtn(a.y - bf16_bits_to_f32(h.y));
    h.z = f32_to_bf16_rtn(a.z); l.z = f32_to_bf16_rtn(a.z - bf16_bits_to_f32(h.z));
    h.w = f32_to_bf16_rtn(a.w); l.w = f32_to_bf16_rtn(a.w - bf16_bits_to_f32(h.w));
    ((ushort4*)Ahi)[i] = h; ((ushort4*)Alo)[i] = l;

    h.x = f32_to_bf16_rtn(b.x); l.x = f32_to_bf16_rtn(b.x - bf16_bits_to_f32(h.x));
    h.y = f32_to_bf16_rtn(b.y); l.y = f32_to_bf16_rtn(b.y - bf16_bits_to_f32(h.y));
    h.z = f32_to_bf16_rtn(b.z); l.z = f32_to_bf16_rtn(b.z - bf16_bits_to_f32(h.z));
    h.w = f32_to_bf16_rtn(b.w); l.w = f32_to_bf16_rtn(b.w - bf16_bits_to_f32(h.w));
    ((ushort4*)Bhi)[i] = h; ((ushort4*)Blo)[i] = l;
}

// ---------------------------------------------------------------------------
// Kernel 2 (presplit, hot path): energies = A @ B^T, split-bf16 3-product GEMM.
// 16x16x32 mfma, 4x4 tiles/wave, 128x128 block.
// History: XOR swizzle -> bank conflicts 0. constexpr dims + unroll (r4):
// VALUBusy 43->23.6. NT C-stores (r5): FETCH 476->427, dur 370->362.
// Residual: MfmaUtil 55 + VALUBusy 24 ~ 79% issue; ~21% hole = per-K-step
// vmcnt(0) drain inside __syncthreads exposing full memory latency 32x.
// r6: DOUBLE-BUFFERED LDS (2x32KB) + COUNTED vmcnt(8) + raw s_barrier
// (T3/T4): next tile's 8 gload_lds stay in flight under the current tile's
// 48 MFMA. + T5 setprio around MFMA cluster. Hazards: buffer overwritten
// only after barrier that follows lgkm-gated consumption; buffer read only
// after own-wave vmcnt(8) + barrier (all waves' loads landed).
// m139 caveat: this was neutral for 16-MFMA/step plain bf16; our 3x MFMA
// density gives the latency 3x more compute to hide under.
// ---------------------------------------------------------------------------
__device__ __forceinline__ void wait_vm8_bar()
{
    asm volatile("s_waitcnt vmcnt(8)" ::: "memory");
    __builtin_amdgcn_s_barrier();
    asm volatile("" ::: "memory");
}
__device__ __forceinline__ void wait_vm0_bar()
{
    asm volatile("s_waitcnt vmcnt(0)" ::: "memory");
    __builtin_amdgcn_s_barrier();
    asm volatile("" ::: "memory");
}
__device__ __forceinline__ void bar_only()
{
    asm volatile("" ::: "memory");
    __builtin_amdgcn_s_barrier();
    asm volatile("" ::: "memory");
}

template<int KC, int NC>
__global__ __launch_bounds__(256) void gemm_presplit(
    const __hip_bfloat16* __restrict__ Ahi, const __hip_bfloat16* __restrict__ Alo,
    const __hip_bfloat16* __restrict__ Bhi, const __hip_bfloat16* __restrict__ Blo,
    float* __restrict__ out, int M, int N, int K)
{
    const int Kd = (KC > 0) ? KC : K;   // compile-time when KC>0
    const int Nd = (NC > 0) ? NC : N;

    // Two 32KB buffers: [0,8K)=Ahi [8K,16K)=Alo [16K,24K)=Bhi [24K,32K)=Blo
    __shared__ char sm[65536];
    const int tid  = threadIdx.x;
    const int lane = tid & 63;
    const int w    = tid >> 6;
    const int bm = blockIdx.y, bn = blockIdx.x;
    const int wm = (w >> 1) * 64;
    const int wn = (w & 1) * 64;

    f32x4 acc[4][4] = {};

    // staging: thread owns LDS chunk (row=(c&1)*64 + tid>>2, pos=tid&3);
    // fetches source chunk (tid&3) ^ ((row>>1)&3) = (tid&3) ^ ((tid>>3)&3)
    const int sfetch = (tid & 3) ^ ((tid >> 3) & 3);
    const size_t offA = (size_t)(bm * 128 + (tid >> 2)) * Kd + sfetch * 8;
    const size_t offB = (size_t)(bn * 128 + (tid >> 2)) * Kd + sfetch * 8;
    const __hip_bfloat16* pAh = Ahi + offA;
    const __hip_bfloat16* pAl = Alo + offA;
    const __hip_bfloat16* pBh = Bhi + offB;
    const __hip_bfloat16* pBl = Blo + offB;
    const size_t half = (size_t)64 * Kd;   // +64 rows
    char* dst0 = sm + tid * 16;

    // read side: fragment chunk = lane>>4, swizzled: ^ ((lane>>1)&3)
    const int rA = lane & 15;
    const int ca = (lane >> 4) ^ ((lane >> 1) & 3);
    const char* aP = sm +         (wm + rA) * 64 + ca * 16;   // A-hi base
    const char* bP = sm + 16384 + (wn + rA) * 64 + ca * 16;   // B-hi base

#define STAGE(BO, kk) do { \
    __builtin_amdgcn_global_load_lds((gas_ptr)(pAh + (kk)),        (lds_ptr_t)(dst0 + (BO)),          16, 0, 0); \
    __builtin_amdgcn_global_load_lds((gas_ptr)(pAh + half + (kk)), (lds_ptr_t)(dst0 + (BO) + 4096),   16, 0, 0); \
    __builtin_amdgcn_global_load_lds((gas_ptr)(pAl + (kk)),        (lds_ptr_t)(dst0 + (BO) + 8192),   16, 0, 0); \
    __builtin_amdgcn_global_load_lds((gas_ptr)(pAl + half + (kk)), (lds_ptr_t)(dst0 + (BO) + 12288),  16, 0, 0); \
    __builtin_amdgcn_global_load_lds((gas_ptr)(pBh + (kk)),        (lds_ptr_t)(dst0 + (BO) + 16384),  16, 0, 0); \
    __builtin_amdgcn_global_load_lds((gas_ptr)(pBh + half + (kk)), (lds_ptr_t)(dst0 + (BO) + 20480),  16, 0, 0); \
    __builtin_amdgcn_global_load_lds((gas_ptr)(pBl + (kk)),        (lds_ptr_t)(dst0 + (BO) + 24576),  16, 0, 0); \
    __builtin_amdgcn_global_load_lds((gas_ptr)(pBl + half + (kk)), (lds_ptr_t)(dst0 + (BO) + 28672),  16, 0, 0); \
} while (0)

#define COMPUTE(BO) do { \
    bf16x8 bh[4], bl[4]; \
    _Pragma("unroll") \
    for (int j = 0; j < 4; ++j) { \
        bh[j] = *(const bf16x8*)(bP + (BO) + j * 1024); \
        bl[j] = *(const bf16x8*)(bP + (BO) + j * 1024 + 8192); \
    } \
    __builtin_amdgcn_s_setprio(1); \
    _Pragma("unroll") \
    for (int i = 0; i < 4; ++i) { \
        bf16x8 ah = *(const bf16x8*)(aP + (BO) + i * 1024); \
        bf16x8 al = *(const bf16x8*)(aP + (BO) + i * 1024 + 8192); \
        _Pragma("unroll") \
        for (int j = 0; j < 4; ++j) { \
            acc[i][j] = __builtin_amdgcn_mfma_f32_16x16x32_bf16(ah, bh[j], acc[i][j], 0, 0, 0); \
            acc[i][j] = __builtin_amdgcn_mfma_f32_16x16x32_bf16(al, bh[j], acc[i][j], 0, 0, 0); \
            acc[i][j] = __builtin_amdgcn_mfma_f32_16x16x32_bf16(ah, bl[j], acc[i][j], 0, 0, 0); \
        } \
    } \
    __builtin_amdgcn_s_setprio(0); \
} while (0)

    // Pipeline: stage t+1 into the other buffer, wait own vmcnt to 8
    // (current buffer's 8 loads landed), barrier, compute; barrier before
    // the buffer can be overwritten. vmcnt never drains to 0 in the loop.
    STAGE(0, 0);
#pragma unroll 2
    for (int k0 = 0; k0 < Kd - 64; k0 += 64) {
        STAGE(32768, k0 + 32);
        wait_vm8_bar();
        COMPUTE(0);
        bar_only();
        STAGE(0, k0 + 64);
        wait_vm8_bar();
        COMPUTE(32768);
        bar_only();
    }
    // tail: k0 = Kd-64
    STAGE(32768, Kd - 32);
    wait_vm8_bar();
    COMPUTE(0);
    bar_only();
    wait_vm0_bar();
    COMPUTE(32768);

#undef STAGE
#undef COMPUTE

    // Epilogue: 16x16 C/D layout col=lane&15, row=(lane>>4)*4+reg (m89/m91).
    // NT stores: C is 256 MB (> L3), zero reuse before softmax streams it.
    const int r0 = bm * 128 + wm + ((lane >> 4) << 2);
    const int c0 = bn * 128 + wn + rA;
#pragma unroll
    for (int i = 0; i < 4; ++i)
#pragma unroll
        for (int j = 0; j < 4; ++j)
#pragma unroll
            for (int r = 0; r < 4; ++r)
                __builtin_nontemporal_store(
                    acc[i][j][r],
                    &out[(size_t)(r0 + i * 16 + r) * Nd + (c0 + j * 16)]);
}

// ---------------------------------------------------------------------------
// Kernel 2b (fallback, ws too small — not expected to run): inline split.
// ---------------------------------------------------------------------------
__global__ __launch_bounds__(256) void gemm_fallback(
    const float* __restrict__ Af, const float* __restrict__ Bf,
    float* __restrict__ out, int M, int N, int K)
{
    __shared__ char sm[32768];
    const int tid  = threadIdx.x;
    const int lane = tid & 63;
    const int w    = tid >> 6;
    const int bm = blockIdx.y, bn = blockIdx.x;
    const int wm = (w >> 1) * 64;
    const int wn = (w & 1) * 64;

    f32x4 acc[4][4] = {};
    const int sfetch = (tid & 3) ^ ((tid >> 3) & 3);
    const int rA = lane & 15;
    const int ca = (lane >> 4) ^ ((lane >> 1) & 3);
    const char* aP = sm +         (wm + rA) * 64 + ca * 16;
    const char* bP = sm + 16384 + (wn + rA) * 64 + ca * 16;

    for (int k0 = 0; k0 < K; k0 += 32) {
        __syncthreads();
#pragma unroll
        for (int c = 0; c < 4; ++c) {
            const bool isA = (c < 2);
            const int row = ((c & 1) << 6) + (tid >> 2);
            const float* src = (isA ? Af + (size_t)(bm * 128 + row) * K
                                    : Bf + (size_t)(bn * 128 + row) * K)
                               + k0 + ((tid & 3) << 3);
            f32x4 v0 = *(const f32x4*)src;
            f32x4 v1 = *(const f32x4*)(src + 4);
            float vv[8] = {v0.x, v0.y, v0.z, v0.w, v1.x, v1.y, v1.z, v1.w};
            bf16x8 h, l;
#pragma unroll
            for (int j = 0; j < 8; ++j) {
                unsigned short hb = f32_to_bf16_rtn(vv[j]);
                unsigned short lb = f32_to_bf16_rtn(vv[j] - bf16_bits_to_f32(hb));
                h[j] = (short)hb; l[j] = (short)lb;
            }
            const int g = row * 64 + sfetch * 16;
            *(bf16x8*)(sm + (isA ? 0 : 16384) + g) = h;
            *(bf16x8*)(sm + (isA ? 8192 : 24576) + g) = l;
        }
        __syncthreads();

        bf16x8 bh[4], bl[4];
#pragma unroll
        for (int j = 0; j < 4; ++j) {
            bh[j] = *(const bf16x8*)(bP + j * 1024);
            bl[j] = *(const bf16x8*)(bP + j * 1024 + 8192);
        }
#pragma unroll
        for (int i = 0; i < 4; ++i) {
            bf16x8 ah = *(const bf16x8*)(aP + i * 1024);
            bf16x8 al = *(const bf16x8*)(aP + i * 1024 + 8192);
#pragma unroll
            for (int j = 0; j < 4; ++j) {
                acc[i][j] = __builtin_amdgcn_mfma_f32_16x16x32_bf16(ah, bh[j], acc[i][j], 0, 0, 0);
                acc[i][j] = __builtin_amdgcn_mfma_f32_16x16x32_bf16(al, bh[j], acc[i][j], 0, 0, 0);
                acc[i][j] = __builtin_amdgcn_mfma_f32_16x16x32_bf16(ah, bl[j], acc[i][j], 0, 0, 0);
            }
        }
    }

    const int r0 = bm * 128 + wm + ((lane >> 4) << 2);
    const int c0 = bn * 128 + wn + rA;
#pragma unroll
    for (int i = 0; i < 4; ++i)
#pragma unroll
        for (int j = 0; j < 4; ++j)
#pragma unroll
            for (int r = 0; r < 4; ++r)
                __builtin_nontemporal_store(
                    acc[i][j][r],
                    &out[(size_t)(r0 + i * 16 + r) * N + (c0 + j * 16)]);
}

// ---------------------------------------------------------------------------
// Kernel 3: in-place row softmax. r0 (3-barrier), r1 (pipeline+syncthreads),
// r3 (pipeline+lgkm-only barriers) all measured the SAME non-gemm remainder
// (~320-350 us) -> softmax-structure theories refuted; remainder likely
// dominated by harness reset/launch overhead. Frozen at the r3 version.
// ---------------------------------------------------------------------------
__device__ __forceinline__ void lgkm_barrier()
{
    asm volatile("s_waitcnt lgkmcnt(0)" ::: "memory");
    __builtin_amdgcn_s_barrier();
    asm volatile("" ::: "memory");
}

__device__ __forceinline__ void softmax_row(
    f32x4 (&v)[8], f32x4 (&vn)[8], const f32x4* __restrict__ pn, bool pref,
    f32x4* __restrict__ pout, int tid, int slot,
    float (*smax)[4], float (*ssum)[4])
{
    if (pref) {
#pragma unroll
        for (int i = 0; i < 8; ++i) vn[i] = pn[tid + (i << 8)];
    }
    float m = -3.402823466e+38f;
#pragma unroll
    for (int i = 0; i < 8; ++i)
        m = fmaxf(m, fmaxf(fmaxf(v[i].x, v[i].y), fmaxf(v[i].z, v[i].w)));
#pragma unroll
    for (int o = 32; o >= 1; o >>= 1) m = fmaxf(m, __shfl_xor(m, o));
    if ((tid & 63) == 0) smax[slot][tid >> 6] = m;
    lgkm_barrier();
    m = fmaxf(fmaxf(smax[slot][0], smax[slot][1]), fmaxf(smax[slot][2], smax[slot][3]));

    float s = 0.f;
#pragma unroll
    for (int i = 0; i < 8; ++i) {
        v[i].x = __expf(v[i].x - m);
        v[i].y = __expf(v[i].y - m);
        v[i].z = __expf(v[i].z - m);
        v[i].w = __expf(v[i].w - m);
        s += (v[i].x + v[i].y) + (v[i].z + v[i].w);
    }
#pragma unroll
    for (int o = 32; o >= 1; o >>= 1) s += __shfl_xor(s, o);
    if ((tid & 63) == 0) ssum[slot][tid >> 6] = s;
    lgkm_barrier();
    s = (ssum[slot][0] + ssum[slot][1]) + (ssum[slot][2] + ssum[slot][3]);
    const float r = 1.0f / s;
#pragma unroll
    for (int i = 0; i < 8; ++i) {
        v[i] *= r;
        __builtin_nontemporal_store(v[i], &pout[tid + (i << 8)]);
    }
}

__global__ __launch_bounds__(256) void softmax_rows_8192(float* __restrict__ d)
{
    const int tid = threadIdx.x;
    __shared__ float smax[2][4], ssum[2][4];

    f32x4* p0 = (f32x4*)(d + (size_t)blockIdx.x * 4 * 8192);
    f32x4 va[8], vb[8];
#pragma unroll
    for (int i = 0; i < 8; ++i) va[i] = p0[tid + (i << 8)];

    softmax_row(va, vb, p0 + 2048, true,  p0,        tid, 0, smax, ssum);
    softmax_row(vb, va, p0 + 4096, true,  p0 + 2048, tid, 1, smax, ssum);
    softmax_row(va, vb, p0 + 6144, true,  p0 + 4096, tid, 0, smax, ssum);
    softmax_row(vb, va, p0,        false, p0 + 6144, tid, 1, smax, ssum);
}

// ---------------------------------------------------------------------------
extern "C" void kernel_launch(void* const* d_in, const int* in_sizes, int n_in,
                              void* d_out, int out_size, void* d_ws, size_t ws_size,
                              hipStream_t stream)
{
    const float* A = (const float*)d_in[0];   // user_emb [M, K] fp32
    const float* B = (const float*)d_in[1];   // id_emb   [N, K] fp32
    float* out = (float*)d_out;               // [M, N] fp32
    const int K = 1024;
    const int M = in_sizes[0] / K;
    const int N = in_sizes[1] / K;
    const size_t elemsA = (size_t)M * K;
    const size_t elemsB = (size_t)N * K;
    const size_t need = 2 * (elemsA + elemsB) * sizeof(unsigned short);

    dim3 grid(N / 128, M / 128);
    const bool presplit = (ws_size >= need) && (M == N) && (K % 64 == 0) && (K >= 128);

    if (presplit) {
        unsigned short* Ahi = (unsigned short*)d_ws;
        unsigned short* Alo = Ahi + elemsA;
        unsigned short* Bhi = Alo + elemsA;
        unsigned short* Blo = Bhi + elemsB;
        const int n4 = (int)(elemsA / 4);
        split_hi_lo<<<(n4 + 255) / 256, 256, 0, stream>>>(A, B, Ahi, Alo, Bhi, Blo, n4);
        if (K == 1024 && N == 8192) {
            gemm_presplit<1024, 8192><<<grid, 256, 0, stream>>>(
                (const __hip_bfloat16*)Ahi, (const __hip_bfloat16*)Alo,
                (const __hip_bfloat16*)Bhi, (const __hip_bfloat16*)Blo,
                out, M, N, K);
        } else {
            gemm_presplit<0, 0><<<grid, 256, 0, stream>>>(
                (const __hip_bfloat16*)Ahi, (const __hip_bfloat16*)Alo,
                (const __hip_bfloat16*)Bhi, (const __hip_bfloat16*)Blo,
                out, M, N, K);
        }
    } else {
        gemm_fallback<<<grid, 256, 0, stream>>>(A, B, out, M, N, K);
    }
    softmax_rows_8192<<<M / 4, 256, 0, stream>>>(out);
}